// Round 16
// baseline (63.843 us; speedup 1.0000x reference)
//
#include <hip/hip_runtime.h>

#define D 8
#define NE 4
#define NS 3
#define NI 5
#define LN_EPS 1e-5f

// wlds layout: per-stage blocks of 144 floats (576B, 16B-aligned):
//   +0   W1 (64, [d][k])  +64 W2T (32, [d][e])  +96 C (32, n-paired)
//   +128 B1 (8)  +136 B2 (4)  +140 pad(4)
// then Wproj (NS*512) at 432, LN (16) at 1968.
#define STAGE_STRIDE 144
#define SOFF_W1  0
#define SOFF_W2T 64
#define SOFF_C   96
#define SOFF_B1  128
#define SOFF_B2  136
#define OFF_WP   432
#define OFF_LN   1968
#define WLDS_SIZE 1984

typedef float f2 __attribute__((ext_vector_type(2)));
typedef float f4 __attribute__((ext_vector_type(4)));

__device__ __forceinline__ f2 max2(f2 a, f2 b) { return __builtin_elementwise_max(a, b); }
__device__ __forceinline__ f2 bc(float s) { return (f2){s, s}; }

// ---- forced VOP3P packed-f32 FMA (gfx90a+/gfx950). op_sel/op_sel_hi give
// free src1 half-broadcast: no splat movs, 1 inst = 2 FMAs. ----
// acc.lo += a.lo*b.lo ; acc.hi += a.hi*b.lo
__device__ __forceinline__ void pk_fma_lo(f2& acc, f2 a, f2 b) {
    asm("v_pk_fma_f32 %0, %1, %2, %0 op_sel:[0,0,0] op_sel_hi:[1,0,1]"
        : "+v"(acc) : "v"(a), "v"(b));
}
// acc.lo += a.lo*b.hi ; acc.hi += a.hi*b.hi
__device__ __forceinline__ void pk_fma_hi(f2& acc, f2 a, f2 b) {
    asm("v_pk_fma_f32 %0, %1, %2, %0 op_sel:[0,1,0] op_sel_hi:[1,1,1]"
        : "+v"(acc) : "v"(a), "v"(b));
}
// element-wise: acc += a*b
__device__ __forceinline__ void pk_fma_ee(f2& acc, f2 a, f2 b) {
    asm("v_pk_fma_f32 %0, %1, %2, %0"
        : "+v"(acc) : "v"(a), "v"(b));
}

// ---------------------------------------------------------------------------
// Setup kernel: C in n-PAIRED layout: C[s*32 + ((n>>1)*8 + d)*2 + (n&1)]
// ---------------------------------------------------------------------------
__global__ void precompute_C_kernel(const float* __restrict__ Bmat,
                                    const float* __restrict__ Wproj,
                                    const float* __restrict__ bproj,
                                    float* __restrict__ C) {
    int idx = threadIdx.x;
    if (idx >= NS * NE * D) return;
    int s = idx / (NE * D);
    int rem = idx % (NE * D);
    int n = rem / D;
    int d = rem % D;
    const float* bm = Bmat + ((size_t)s * NE + n) * 64;
    const float* wp = Wproj + ((size_t)s * D + d) * 64;
    float acc = bproj[s * D + d];
    #pragma unroll
    for (int k = 0; k < 64; ++k) acc += bm[k] * wp[k];
    C[s * 32 + ((n >> 1) * 8 + d) * 2 + (n & 1)] = acc;
}

__device__ __forceinline__ float fast_tanh(float x) {
    float e = __expf(2.f * x);
    return 1.f - 2.f * __builtin_amdgcn_rcpf(e + 1.f);
}

__device__ __forceinline__ f4 ld4(const float* p) {
    return *reinterpret_cast<const f4*>(p);
}

// ---------------------------------------------------------------------------
// Main kernel: R15 structure (1 thread/row, f2 n-packing, t in regs, per-stage
// LDS blocks, one gated pointer, no spill) + R16: ALL broadcast FMAs forced to
// v_pk_fma_f32 via inline asm with op_sel half-broadcast. Evidence: R15 busy
// time = scalarized issue rate (20K inst/thread vs 10K packed) — the backend
// does not pattern-match splat-operand v2f32 fma to VOP3P. t stored as f2
// pairs tp[d][kp] so src1 comes straight from register pairs; W1/W2T rows
// feed src1 via f4 .lo/.hi subregister pairs; H2 .x/.y selected by op_sel
// (extract movs deleted).
// ---------------------------------------------------------------------------
__global__ __launch_bounds__(256, 2) void whisp_kernel(
    const float* __restrict__ cl, const float* __restrict__ cd,
    const float* __restrict__ re_log, const float* __restrict__ mach,
    const float* __restrict__ alpha, const float* __restrict__ u,
    const float* __restrict__ We, const float* __restrict__ be,
    const float* __restrict__ Wproj,
    const float* __restrict__ Wr1, const float* __restrict__ br1,
    const float* __restrict__ Wr2, const float* __restrict__ br2,
    const float* __restrict__ ln_g, const float* __restrict__ ln_b,
    const float* __restrict__ Wout, const float* __restrict__ bout,
    const float* __restrict__ fg, const float* __restrict__ fb,
    const float* __restrict__ Wcst, const float* __restrict__ bcst,
    const float* __restrict__ Wcl, const float* __restrict__ bcl,
    const float* __restrict__ Cpre,
    float* __restrict__ out, int B)
{
    __shared__ __align__(16) float wlds[WLDS_SIZE];   // 7936 B
    __shared__ __align__(16) f4 ubuf[2 * 256];        // 8192 B (per-thread uu)
    __shared__ float souts[256 * 19];                 // 19456 B

    const int tid = threadIdx.x;
    const int row0 = blockIdx.x * 256 + tid;
    const bool active = (row0 < B);
    const int row = active ? row0 : (B - 1);

    // ---- stage hot-loop weights into per-stage LDS blocks ----
    for (int i = tid; i < NS * 64; i += 256) {         // W1 natural
        int s = i / 64, j = i % 64;
        wlds[s * STAGE_STRIDE + SOFF_W1 + j] = Wr1[i];
    }
    for (int i = tid; i < NS * 32; i += 256) {         // W2 -> [d][e]
        int s = i / 32, j = i % 32, d = j / 4, e = j % 4;
        wlds[s * STAGE_STRIDE + SOFF_W2T + j] = Wr2[s * 32 + e * 8 + d];
    }
    for (int i = tid; i < NS * 32; i += 256) {         // C (n-paired)
        int s = i / 32, j = i % 32;
        wlds[s * STAGE_STRIDE + SOFF_C + j] = Cpre[i];
    }
    for (int i = tid; i < NS * 8; i += 256) {          // B1
        int s = i / 8, j = i % 8;
        wlds[s * STAGE_STRIDE + SOFF_B1 + j] = br1[i];
    }
    for (int i = tid; i < NS * 4; i += 256) {          // B2
        int s = i / 4, j = i % 4;
        wlds[s * STAGE_STRIDE + SOFF_B2 + j] = br2[i];
    }
    for (int i = tid; i < 1536; i += 256) wlds[OFF_WP + i] = Wproj[i];
    for (int i = tid; i < 8; i += 256) { wlds[OFF_LN + i] = ln_g[i]; wlds[OFF_LN + 8 + i] = ln_b[i]; }

    // ---- per-row inputs; uu stashed in per-thread LDS ----
    {
        const f4* up = reinterpret_cast<const f4*>(u + (size_t)row * D);
        ubuf[tid]       = up[0];
        ubuf[256 + tid] = up[1];
    }
    float xs[NE] = { cl[row], cd[row], re_log[row], mach[row] };
    float al = alpha[row];

    // ---- embedding -> E2[nn][d] = (E[2nn][d], E[2nn+1][d]) ----
    f2 E2[2][D];
    #pragma unroll
    for (int nn = 0; nn < 2; ++nn) {
        #pragma unroll
        for (int d = 0; d < D; ++d) {
            int na = 2 * nn, nb = 2 * nn + 1;
            float pa = We[na * 16 + d * 2] * xs[na] + We[na * 16 + d * 2 + 1] * al + be[na * D + d];
            float pb = We[nb * 16 + d * 2] * xs[nb] + We[nb * 16 + d * 2 + 1] * al + be[nb * D + d];
            E2[nn][d] = (f2){ fast_tanh(pa), fast_tanh(pb) };
        }
    }

    __syncthreads();   // wlds + ubuf ready

    int zero = 0;      // opaque 0: blocks LICM of broadcast weight loads

    // ---- outer stages ----
    #pragma unroll 1
    for (int s = 0; s < NS; ++s) {
        const float* stage_base = wlds + s * STAGE_STRIDE;

        // tp[d][kp] = (t[d][2kp], t[d][2kp+1]) in REGISTERS (f32 exact)
        f2 tp[D][4];
        {
            f4 uq0 = ubuf[tid], uq1 = ubuf[256 + tid];
            f2 uu2[4] = { uq0.lo, uq0.hi, uq1.lo, uq1.hi };
            const float* Wp = wlds + OFF_WP + s * 512;
            #pragma unroll
            for (int d = 0; d < D; ++d) {
                #pragma unroll
                for (int kp = 0; kp < 4; ++kp) {
                    int i0 = 2 * kp, i1 = 2 * kp + 1;
                    f4 a0 = ld4(Wp + d * 64 + i0 * 8);
                    f4 a1 = ld4(Wp + d * 64 + i0 * 8 + 4);
                    f4 b0 = ld4(Wp + d * 64 + i1 * 8);
                    f4 b1 = ld4(Wp + d * 64 + i1 * 8 + 4);
                    f2 accA = uu2[0] * a0.lo;
                    pk_fma_ee(accA, uu2[1], a0.hi);
                    pk_fma_ee(accA, uu2[2], a1.lo);
                    pk_fma_ee(accA, uu2[3], a1.hi);
                    f2 accB = uu2[0] * b0.lo;
                    pk_fma_ee(accB, uu2[1], b0.hi);
                    pk_fma_ee(accB, uu2[2], b1.lo);
                    pk_fma_ee(accB, uu2[3], b1.hi);
                    tp[d][kp] = (f2){ accA.x + accA.y, accB.x + accB.y };
                }
            }
        }

        #pragma unroll 1
        for (int it = 0; it < NI; ++it) {
            // ONE gated base; all weight reads are imm offsets off it
            asm volatile("" : "+v"(zero));
            const float* sb = stage_base + zero;

            // H init from n-paired C
            f2 H2[2][D];
            #pragma unroll
            for (int nn = 0; nn < 2; ++nn) {
                #pragma unroll
                for (int dp = 0; dp < 4; ++dp) {
                    f4 cq = ld4(sb + SOFF_C + nn * 16 + dp * 4);
                    H2[nn][2 * dp]     = cq.lo;
                    H2[nn][2 * dp + 1] = cq.hi;
                }
            }
            // H2[nn][d] += sum_i E2[nn][i] * t[d][i]  (t pairs, op_sel bcast)
            #pragma unroll
            for (int d = 0; d < D; ++d) {
                #pragma unroll
                for (int nn = 0; nn < 2; ++nn) {
                    f2 acc = H2[nn][d];
                    pk_fma_lo(acc, E2[nn][0], tp[d][0]);
                    pk_fma_hi(acc, E2[nn][1], tp[d][0]);
                    pk_fma_lo(acc, E2[nn][2], tp[d][1]);
                    pk_fma_hi(acc, E2[nn][3], tp[d][1]);
                    pk_fma_lo(acc, E2[nn][4], tp[d][2]);
                    pk_fma_hi(acc, E2[nn][5], tp[d][2]);
                    pk_fma_lo(acc, E2[nn][6], tp[d][3]);
                    pk_fma_hi(acc, E2[nn][7], tp[d][3]);
                    H2[nn][d] = acc;
                }
            }

            // lg init from B2
            f2 lg2[2][NE];
            {
                float b20 = sb[SOFF_B2 + 0], b21 = sb[SOFF_B2 + 1];
                float b22 = sb[SOFF_B2 + 2], b23 = sb[SOFF_B2 + 3];
                #pragma unroll
                for (int nn = 0; nn < 2; ++nn) {
                    lg2[nn][0] = bc(b20); lg2[nn][1] = bc(b21);
                    lg2[nn][2] = bc(b22); lg2[nn][3] = bc(b23);
                }
            }

            // fused routing: per d compute r2 then accumulate into lg
            #pragma unroll
            for (int d = 0; d < D; ++d) {
                f4 wa = ld4(sb + SOFF_W1 + d * 8);
                f4 wb = ld4(sb + SOFF_W1 + d * 8 + 4);
                f4 w2 = ld4(sb + SOFF_W2T + d * 4);
                float b1d = sb[SOFF_B1 + d];
                #pragma unroll
                for (int nn = 0; nn < 2; ++nn) {
                    f2 acc = bc(b1d);
                    pk_fma_lo(acc, H2[nn][0], wa.lo);
                    pk_fma_hi(acc, H2[nn][1], wa.lo);
                    pk_fma_lo(acc, H2[nn][2], wa.hi);
                    pk_fma_hi(acc, H2[nn][3], wa.hi);
                    pk_fma_lo(acc, H2[nn][4], wb.lo);
                    pk_fma_hi(acc, H2[nn][5], wb.lo);
                    pk_fma_lo(acc, H2[nn][6], wb.hi);
                    pk_fma_hi(acc, H2[nn][7], wb.hi);
                    f2 r2 = max2(acc, bc(0.f));
                    pk_fma_lo(lg2[nn][0], r2, w2.lo);
                    pk_fma_hi(lg2[nn][1], r2, w2.lo);
                    pk_fma_lo(lg2[nn][2], r2, w2.hi);
                    pk_fma_hi(lg2[nn][3], r2, w2.hi);
                }
            }

            // packed softmax over e (per n; n's in f2 lanes)
            f2 sm2[2][NE];
            #pragma unroll
            for (int nn = 0; nn < 2; ++nn) {
                f2 m2 = max2(max2(lg2[nn][0], lg2[nn][1]), max2(lg2[nn][2], lg2[nn][3]));
                f2 ee[NE];
                #pragma unroll
                for (int e = 0; e < NE; ++e) {
                    f2 tt = lg2[nn][e] - m2;
                    ee[e] = (f2){ __expf(tt.x), __expf(tt.y) };
                }
                f2 s2 = (ee[0] + ee[1]) + (ee[2] + ee[3]);
                f2 inv2 = (f2){ __builtin_amdgcn_rcpf(s2.x), __builtin_amdgcn_rcpf(s2.y) };
                #pragma unroll
                for (int e = 0; e < NE; ++e) sm2[nn][e] = ee[e] * inv2;
            }

            // E2[nn][d] += sum_e sm2[nn][e] * H[e][d]  (H halves via op_sel)
            #pragma unroll
            for (int d = 0; d < D; ++d) {
                #pragma unroll
                for (int nn = 0; nn < 2; ++nn) {
                    f2 acc = E2[nn][d];
                    pk_fma_lo(acc, sm2[nn][0], H2[0][d]);
                    pk_fma_hi(acc, sm2[nn][1], H2[0][d]);
                    pk_fma_lo(acc, sm2[nn][2], H2[1][d]);
                    pk_fma_hi(acc, sm2[nn][3], H2[1][d]);
                    E2[nn][d] = acc;
                }
            }
        }

        // post-stage LayerNorm (params from LDS; packed math)
        float lngv[8], lnbv[8];
        {
            f4 g0 = ld4(wlds + OFF_LN),     g1 = ld4(wlds + OFF_LN + 4);
            f4 b0 = ld4(wlds + OFF_LN + 8), b1 = ld4(wlds + OFF_LN + 12);
            lngv[0]=g0.x; lngv[1]=g0.y; lngv[2]=g0.z; lngv[3]=g0.w;
            lngv[4]=g1.x; lngv[5]=g1.y; lngv[6]=g1.z; lngv[7]=g1.w;
            lnbv[0]=b0.x; lnbv[1]=b0.y; lnbv[2]=b0.z; lnbv[3]=b0.w;
            lnbv[4]=b1.x; lnbv[5]=b1.y; lnbv[6]=b1.z; lnbv[7]=b1.w;
        }
        #pragma unroll
        for (int nn = 0; nn < 2; ++nn) {
            f2 s2 = (E2[nn][0] + E2[nn][1]) + (E2[nn][2] + E2[nn][3]);
            s2 = s2 + (E2[nn][4] + E2[nn][5]) + (E2[nn][6] + E2[nn][7]);
            f2 m2 = s2 * bc(0.125f);
            f2 v2 = bc(0.f);
            #pragma unroll
            for (int d = 0; d < D; ++d) { f2 c = E2[nn][d] - m2; pk_fma_ee(v2, c, c); }
            v2 = v2 * bc(0.125f);
            f2 inv2 = (f2){ __builtin_amdgcn_rsqf(v2.x + LN_EPS),
                            __builtin_amdgcn_rsqf(v2.y + LN_EPS) };
            #pragma unroll
            for (int d = 0; d < D; ++d) {
                f2 r = bc(lnbv[d]);
                pk_fma_ee(r, (E2[nn][d] - m2) * inv2, bc(lngv[d]));
                E2[nn][d] = r;
            }
        }
    }

    // ---- final mixing (one-time global weights; scalar epilogue) ----
    float lgf[NE];
    #pragma unroll
    for (int e = 0; e < NE; ++e) {
        float a0 = bout[e], a1 = 0.f;
        #pragma unroll
        for (int d = 0; d < D; ++d) {
            a0 = fmaf(E2[0][d].x, Wout[e * 32 + 0 * D + d], a0);
            a1 = fmaf(E2[0][d].y, Wout[e * 32 + 1 * D + d], a1);
            a0 = fmaf(E2[1][d].x, Wout[e * 32 + 2 * D + d], a0);
            a1 = fmaf(E2[1][d].y, Wout[e * 32 + 3 * D + d], a1);
        }
        lgf[e] = a0 + a1;
    }
    float mx = fmaxf(fmaxf(lgf[0], lgf[1]), fmaxf(lgf[2], lgf[3]));
    float w0 = __expf(lgf[0] - mx), w1 = __expf(lgf[1] - mx);
    float w2 = __expf(lgf[2] - mx), w3 = __expf(lgf[3] - mx);
    float winv = __builtin_amdgcn_rcpf((w0 + w1) + (w2 + w3));
    w0 *= winv; w1 *= winv; w2 *= winv; w3 *= winv;

    float z[D];
    #pragma unroll
    for (int d = 0; d < D; ++d) {
        float a0 = w0 * E2[0][d].x;
        float a1 = w1 * E2[0][d].y;
        a0 = fmaf(w2, E2[1][d].x, a0);
        a1 = fmaf(w3, E2[1][d].y, a1);
        z[d] = a0 + a1;
    }
    float zm = 0.f;
    #pragma unroll
    for (int d = 0; d < D; ++d) zm += z[d];
    zm *= (1.f / D);
    float zv = 0.f;
    #pragma unroll
    for (int d = 0; d < D; ++d) { float c = z[d] - zm; zv = fmaf(c, c, zv); }
    zv *= (1.f / D);
    float zinv = __builtin_amdgcn_rsqf(zv + LN_EPS);
    #pragma unroll
    for (int d = 0; d < D; ++d)
        z[d] = (z[d] - zm) * zinv * fg[d] + fb[d];

    // heads
    float zout[19];
    #pragma unroll
    for (int k = 0; k < 18; ++k) {
        float a0 = bcst[k], a1 = 0.f;
        #pragma unroll
        for (int d = 0; d < D; d += 2) {
            a0 = fmaf(z[d],     Wcst[k * D + d],     a0);
            a1 = fmaf(z[d + 1], Wcst[k * D + d + 1], a1);
        }
        zout[k] = a0 + a1;
    }
    {
        float a0 = bcl[0], a1 = 0.f;
        #pragma unroll
        for (int d = 0; d < D; d += 2) {
            a0 = fmaf(z[d],     Wcl[d],     a0);
            a1 = fmaf(z[d + 1], Wcl[d + 1], a1);
        }
        zout[18] = a0 + a1;
    }

    // stage via LDS for coalesced stores
    if (active) {
        #pragma unroll
        for (int k = 0; k < 19; ++k) souts[tid * 19 + k] = zout[k];
    }
    __syncthreads();

    const int base = blockIdx.x * 256;
    int nrows = B - base;
    if (nrows > 256) nrows = 256;
    if (nrows > 0) {
        const int cnt = nrows * 19;
        for (int i = tid; i < cnt; i += 256)
            out[(size_t)base * 19 + i] = souts[i];
    }
}

extern "C" void kernel_launch(void* const* d_in, const int* in_sizes, int n_in,
                              void* d_out, int out_size, void* d_ws, size_t ws_size,
                              hipStream_t stream) {
    const float* cl     = (const float*)d_in[0];
    const float* cd     = (const float*)d_in[1];
    const float* re_log = (const float*)d_in[2];
    const float* mach   = (const float*)d_in[3];
    const float* alpha  = (const float*)d_in[4];
    const float* u      = (const float*)d_in[5];
    const float* We     = (const float*)d_in[6];
    const float* be     = (const float*)d_in[7];
    const float* Bmat   = (const float*)d_in[8];
    const float* Wproj  = (const float*)d_in[9];
    const float* bproj  = (const float*)d_in[10];
    const float* Wr1    = (const float*)d_in[11];
    const float* br1    = (const float*)d_in[12];
    const float* Wr2    = (const float*)d_in[13];
    const float* br2    = (const float*)d_in[14];
    const float* ln_g   = (const float*)d_in[15];
    const float* ln_b   = (const float*)d_in[16];
    const float* Wout   = (const float*)d_in[17];
    const float* bout   = (const float*)d_in[18];
    const float* fg     = (const float*)d_in[19];
    const float* fb     = (const float*)d_in[20];
    const float* Wcst   = (const float*)d_in[21];
    const float* bcst   = (const float*)d_in[22];
    const float* Wcl    = (const float*)d_in[23];
    const float* bcl    = (const float*)d_in[24];

    float* Cpre = (float*)d_ws;   // 96 floats (n-paired layout)
    const int B = in_sizes[0];

    hipLaunchKernelGGL(precompute_C_kernel, dim3(1), dim3(128), 0, stream,
                       Bmat, Wproj, bproj, Cpre);

    const int blocks = (B + 255) / 256;
    hipLaunchKernelGGL(whisp_kernel, dim3(blocks), dim3(256), 0, stream,
                       cl, cd, re_log, mach, alpha, u, We, be, Wproj,
                       Wr1, br1, Wr2, br2, ln_g, ln_b, Wout, bout, fg, fb,
                       Wcst, bcst, Wcl, bcl, Cpre, (float*)d_out, B);
}